// Round 1
// baseline (30.361 us; speedup 1.0000x reference)
//
#include <hip/hip_runtime.h>

// Problem constants (fixed by setup_inputs):
//   N_TRAILS=256, N_STEPS=16, N_NODES=4096
//   trail edges: e = i*256+t (i<15), u=e, v=e+256
//   dev edges:   e = 3840 + i*255 + t (t<255), u=i*256+t, v=u+1
#define N_TRAILS 256
#define N_STEPS 16
#define N_NODES 4096
#define N_TRAIL_E 3840
#define N_DEV_E 4080
#define N_EDGES 7920

// d_out layout (f32, concatenated return order):
//   xyz (4096,3) | reactions (4096,3) | lengths (7920,1) | loads (4096,3) | forces (7920,1)
#define OFF_XYZ 0
#define OFF_REACT 12288
#define OFF_LEN 24576
#define OFF_LOADS 32496
#define OFF_FORCES 44784

__global__ void init_copy(const float* __restrict__ loads,
                          const float* __restrict__ forces0,
                          float* __restrict__ out) {
    int idx = blockIdx.x * blockDim.x + threadIdx.x;
    // zero reactions for rows 0..14 (row 15 written by scan kernel)
    if (idx < (N_TRAIL_E * 3)) out[OFF_REACT + idx] = 0.0f;
    // loads passthrough
    if (idx < (N_NODES * 3)) out[OFF_LOADS + idx] = loads[idx];
    // deviation-edge forces passthrough (trail-edge forces written by scan kernel)
    if (idx < N_DEV_E) out[OFF_FORCES + N_TRAIL_E + idx] = forces0[N_TRAIL_E + idx];
}

__global__ __launch_bounds__(256) void cem_scan(
    const float* __restrict__ xyz0,
    const float* __restrict__ loads,
    const float* __restrict__ lengths0,
    const float* __restrict__ planes,
    const float* __restrict__ forces0,
    float* __restrict__ out) {
    __shared__ float sx[N_NODES * 3];  // 48 KiB: final xyz, filled row by row
    const int t = threadIdx.x;

    // row 0 positions = xyz0[sequences[0]] = xyz0[0..255]
    float px = xyz0[3 * t + 0];
    float py = xyz0[3 * t + 1];
    float pz = xyz0[3 * t + 2];
    float rx = 0.f, ry = 0.f, rz = 0.f;  // residuals carry

    for (int i = 0; i < N_STEPS; ++i) {
        const int n = i * N_TRAILS + t;

        // xyz[row i] = position carried into this step (pre-update)
        out[OFF_XYZ + 3 * n + 0] = px;
        out[OFF_XYZ + 3 * n + 1] = py;
        out[OFF_XYZ + 3 * n + 2] = pz;
        sx[3 * n + 0] = px;
        sx[3 * n + 1] = py;
        sx[3 * n + 2] = pz;
        __syncthreads();

        // deviation from the (at most 2) incident deviation edges of row i
        float dx = 0.f, dy = 0.f, dz = 0.f;
        const int ebase = N_TRAIL_E + i * (N_TRAILS - 1);
        if (t > 0) {
            // edge eL: (i,t-1) -> (i,t); incidence[eL, n] = -1; vec = x[t]-x[t-1]
            float vx = px - sx[3 * (n - 1) + 0];
            float vy = py - sx[3 * (n - 1) + 1];
            float vz = pz - sx[3 * (n - 1) + 2];
            float s = vx * vx + vy * vy + vz * vz;
            float inv = (s == 0.f) ? 1.f : (1.f / sqrtf(s));
            float f = forces0[ebase + t - 1];
            dx -= f * (vx * inv);
            dy -= f * (vy * inv);
            dz -= f * (vz * inv);
        }
        if (t < N_TRAILS - 1) {
            // edge eR: (i,t) -> (i,t+1); incidence[eR, n] = +1; vec = x[t+1]-x[t]
            float vx = sx[3 * (n + 1) + 0] - px;
            float vy = sx[3 * (n + 1) + 1] - py;
            float vz = sx[3 * (n + 1) + 2] - pz;
            float s = vx * vx + vy * vy + vz * vz;
            float inv = (s == 0.f) ? 1.f : (1.f / sqrtf(s));
            float f = forces0[ebase + t];
            dx += f * (vx * inv);
            dy += f * (vy * inv);
            dz += f * (vz * inv);
        }

        // residuals = residuals - deviation - loads[n]
        rx = rx - dx - loads[3 * n + 0];
        ry = ry - dy - loads[3 * n + 1];
        rz = rz - dz - loads[3 * n + 2];

        // plane logic
        float ox = planes[6 * n + 0], oy = planes[6 * n + 1], oz = planes[6 * n + 2];
        float nx = planes[6 * n + 3], ny = planes[6 * n + 4], nz = planes[6 * n + 5];
        bool zero_n = (fabsf(nx) <= 1e-8f) && (fabsf(ny) <= 1e-8f) && (fabsf(nz) <= 1e-8f);
        if (zero_n) { nx = 1.f; ny = 1.f; nz = 1.f; }
        float cos_nop = zero_n ? 0.f
                               : (nx * (ox - px) + ny * (oy - py) + nz * (oz - pz));
        bool zero_r = (fabsf(rx) <= 1e-8f) && (fabsf(ry) <= 1e-8f) && (fabsf(rz) <= 1e-8f);
        float rsx = zero_r ? 1.f : rx;
        float rsy = zero_r ? 1.f : ry;
        float rsz = zero_r ? 1.f : rz;
        float s2 = rsx * rsx + rsy * rsy + rsz * rsz;
        float inv2 = (s2 == 0.f) ? 1.f : (1.f / sqrtf(s2));
        float denom = nx * (rsx * inv2) + ny * (rsy * inv2) + nz * (rsz * inv2);
        float len_plane = zero_r ? 0.f : (cos_nop / denom);
        float l0 = lengths0[n];
        float L = (l0 != 0.f) ? l0 : len_plane;

        // per-step outputs
        float rn = sqrtf(rx * rx + ry * ry + rz * rz);
        if (i < N_STEPS - 1) {
            // trail edge e = i*256 + t gets |residual| * sign(L>=0)
            out[OFF_FORCES + i * N_TRAILS + t] = rn * ((L < 0.f) ? -1.f : 1.f);
        } else {
            // reactions[row 15] = final residuals
            out[OFF_REACT + 3 * n + 0] = rx;
            out[OFF_REACT + 3 * n + 1] = ry;
            out[OFF_REACT + 3 * n + 2] = rz;
        }

        // xyz_next = xyz + L * safe_normalize(residuals)
        float sr = rx * rx + ry * ry + rz * rz;
        float invr = (sr == 0.f) ? 1.f : (1.f / sqrtf(sr));
        px = px + L * (rx * invr);
        py = py + L * (ry * invr);
        pz = pz + L * (rz * invr);
        // no second barrier needed: next iteration writes a disjoint sx row
    }

    // lengths over all edges from LDS-resident final xyz
    for (int e = t; e < N_EDGES; e += N_TRAILS) {
        int u, v;
        if (e < N_TRAIL_E) {
            u = e;
            v = e + N_TRAILS;
        } else {
            int k = e - N_TRAIL_E;
            int i2 = k / (N_TRAILS - 1);
            int tt = k - i2 * (N_TRAILS - 1);
            u = i2 * N_TRAILS + tt;
            v = u + 1;
        }
        float vx = sx[3 * v + 0] - sx[3 * u + 0];
        float vy = sx[3 * v + 1] - sx[3 * u + 1];
        float vz = sx[3 * v + 2] - sx[3 * u + 2];
        out[OFF_LEN + e] = sqrtf(vx * vx + vy * vy + vz * vz);
    }
}

extern "C" void kernel_launch(void* const* d_in, const int* in_sizes, int n_in,
                              void* d_out, int out_size, void* d_ws, size_t ws_size,
                              hipStream_t stream) {
    const float* xyz0     = (const float*)d_in[0];
    const float* loads    = (const float*)d_in[1];
    const float* lengths0 = (const float*)d_in[2];
    const float* planes   = (const float*)d_in[3];
    const float* forces0  = (const float*)d_in[4];
    float* out = (float*)d_out;

    // 48*256 = 12288 threads covers the largest copy segment
    init_copy<<<48, 256, 0, stream>>>(loads, forces0, out);
    cem_scan<<<1, 256, 0, stream>>>(xyz0, loads, lengths0, planes, forces0, out);
}

// Round 2
// 19.647 us; speedup vs baseline: 1.5453x; 1.5453x over previous
//
#include <hip/hip_runtime.h>

// Problem constants (fixed by setup_inputs):
//   N_TRAILS=256, N_STEPS=16, N_NODES=4096
//   trail edges: e = i*256+t (i<15), u=e, v=e+256
//   dev edges:   e = 3840 + i*255 + t (t<255), u=i*256+t, v=u+1
#define N_TRAILS 256
#define N_STEPS 16
#define N_NODES 4096
#define N_TRAIL_E 3840
#define N_DEV_E 4080
#define N_EDGES 7920

// d_out layout (f32, concatenated return order):
//   xyz (4096,3) | reactions (4096,3) | lengths (7920,1) | loads (4096,3) | forces (7920,1)
#define OFF_XYZ 0
#define OFF_REACT 12288
#define OFF_LEN 24576
#define OFF_LOADS 32496
#define OFF_FORCES 44784

__global__ __launch_bounds__(256, 1) void cem_fused(
    const float* __restrict__ xyz0,
    const float* __restrict__ loads,
    const float* __restrict__ lengths0,
    const float* __restrict__ planes,
    const float* __restrict__ forces0,
    float* __restrict__ out) {
    const int t = threadIdx.x;

    if (blockIdx.x != 0) {
        // ---- copy/zero blocks (blocks 1..48) ----
        int idx = (blockIdx.x - 1) * 256 + t;
        // zero reactions rows 0..14 (row 15 written by scan block)
        if (idx < (N_TRAIL_E * 3)) out[OFF_REACT + idx] = 0.0f;
        // loads passthrough
        if (idx < (N_NODES * 3)) out[OFF_LOADS + idx] = loads[idx];
        // deviation-edge forces passthrough
        if (idx < N_DEV_E) out[OFF_FORCES + N_TRAIL_E + idx] = forces0[N_TRAIL_E + idx];
        return;
    }

    // ---- scan block (block 0): one thread per trail ----
    // 2-row ping-pong buffer for neighbor positions (stride 3 is coprime with
    // 32 banks -> conflict-free).
    __shared__ float row[2][N_TRAILS * 3];

    // Preload ALL per-step per-thread data into registers up front so the HBM
    // latency is paid once, overlapped, instead of per step on the critical
    // path. 192 floats/thread; __launch_bounds__(256,1) permits up to 512 VGPR.
    float pl[N_STEPS][3];   // loads[n]
    float pp[N_STEPS][6];   // planes[n]
    float l0[N_STEPS];      // lengths0[n]
    float fL[N_STEPS];      // forces0[left dev edge]
    float fR[N_STEPS];      // forces0[right dev edge]
#pragma unroll
    for (int i = 0; i < N_STEPS; ++i) {
        const int n = i * N_TRAILS + t;
        pl[i][0] = loads[3 * n + 0];
        pl[i][1] = loads[3 * n + 1];
        pl[i][2] = loads[3 * n + 2];
        const float2* p2 = (const float2*)(planes + 6 * n);  // 8B-aligned
        float2 a = p2[0], b = p2[1], c = p2[2];
        pp[i][0] = a.x; pp[i][1] = a.y; pp[i][2] = b.x;
        pp[i][3] = b.y; pp[i][4] = c.x; pp[i][5] = c.y;
        l0[i] = lengths0[n];
        const int ebase = N_TRAIL_E + i * (N_TRAILS - 1);
        fL[i] = (t > 0) ? forces0[ebase + t - 1] : 0.0f;
        fR[i] = (t < N_TRAILS - 1) ? forces0[ebase + t] : 0.0f;
    }

    // row 0 positions = xyz0[sequences[0]] = xyz0[0..255]
    float px = xyz0[3 * t + 0];
    float py = xyz0[3 * t + 1];
    float pz = xyz0[3 * t + 2];
    float rx = 0.f, ry = 0.f, rz = 0.f;  // residuals carry

#pragma unroll
    for (int i = 0; i < N_STEPS; ++i) {
        const int n = i * N_TRAILS + t;
        float* r = row[i & 1];

        // xyz[row i] = position carried into this step (pre-update)
        out[OFF_XYZ + 3 * n + 0] = px;
        out[OFF_XYZ + 3 * n + 1] = py;
        out[OFF_XYZ + 3 * n + 2] = pz;
        r[3 * t + 0] = px;
        r[3 * t + 1] = py;
        r[3 * t + 2] = pz;
        __syncthreads();
        // One barrier per step is safe: step i reads row[i&1]; step i+1 writes
        // the other buffer; a wave can only reach step i+2's writes to row[i&1]
        // after ALL waves passed step i+1's barrier, which is after their step-i
        // reads.

        // deviation from the (at most 2) incident deviation edges of row i
        float dx = 0.f, dy = 0.f, dz = 0.f;
        if (t > 0) {
            // edge eL: (i,t-1)->(i,t); incidence[eL,n] = -1; vec = x[t]-x[t-1]
            float vx = px - r[3 * (t - 1) + 0];
            float vy = py - r[3 * (t - 1) + 1];
            float vz = pz - r[3 * (t - 1) + 2];
            float s = vx * vx + vy * vy + vz * vz;
            float inv = (s == 0.f) ? 1.f : (1.f / sqrtf(s));
            float f = fL[i];
            dx -= f * (vx * inv);
            dy -= f * (vy * inv);
            dz -= f * (vz * inv);
        }
        if (t < N_TRAILS - 1) {
            // edge eR: (i,t)->(i,t+1); incidence[eR,n] = +1; vec = x[t+1]-x[t]
            float vx = r[3 * (t + 1) + 0] - px;
            float vy = r[3 * (t + 1) + 1] - py;
            float vz = r[3 * (t + 1) + 2] - pz;
            float s = vx * vx + vy * vy + vz * vz;
            float inv = (s == 0.f) ? 1.f : (1.f / sqrtf(s));
            float f = fR[i];
            dx += f * (vx * inv);
            dy += f * (vy * inv);
            dz += f * (vz * inv);
            // dev-edge length: row-i positions ARE the final xyz for row i,
            // so |x[t+1]-x[t]| is this dev edge's final length.
            out[OFF_LEN + N_TRAIL_E + i * (N_TRAILS - 1) + t] = sqrtf(s);
        }

        // residuals = residuals - deviation - loads[n]
        rx = rx - dx - pl[i][0];
        ry = ry - dy - pl[i][1];
        rz = rz - dz - pl[i][2];

        // plane logic
        float ox = pp[i][0], oy = pp[i][1], oz = pp[i][2];
        float nx = pp[i][3], ny = pp[i][4], nz = pp[i][5];
        bool zero_n = (fabsf(nx) <= 1e-8f) && (fabsf(ny) <= 1e-8f) && (fabsf(nz) <= 1e-8f);
        if (zero_n) { nx = 1.f; ny = 1.f; nz = 1.f; }
        float cos_nop = zero_n ? 0.f
                               : (nx * (ox - px) + ny * (oy - py) + nz * (oz - pz));
        bool zero_r = (fabsf(rx) <= 1e-8f) && (fabsf(ry) <= 1e-8f) && (fabsf(rz) <= 1e-8f);
        float rsx = zero_r ? 1.f : rx;
        float rsy = zero_r ? 1.f : ry;
        float rsz = zero_r ? 1.f : rz;
        float s2 = rsx * rsx + rsy * rsy + rsz * rsz;
        float inv2 = (s2 == 0.f) ? 1.f : (1.f / sqrtf(s2));
        float denom = nx * (rsx * inv2) + ny * (rsy * inv2) + nz * (rsz * inv2);
        float len_plane = zero_r ? 0.f : (cos_nop / denom);
        float l0v = l0[i];
        float L = (l0v != 0.f) ? l0v : len_plane;

        float sr = rx * rx + ry * ry + rz * rz;
        float rn = sqrtf(sr);
        if (i < N_STEPS - 1) {
            // trail edge e = i*256+t: force = |res| * sign(L>=0)
            out[OFF_FORCES + i * N_TRAILS + t] = rn * ((L < 0.f) ? -1.f : 1.f);
            // trail edge length = |xyz_next - xyz| = |L| * |normalize(res)|
            out[OFF_LEN + i * N_TRAILS + t] = (sr == 0.f) ? 0.f : fabsf(L);
        } else {
            // reactions[row 15] = final residuals
            out[OFF_REACT + 3 * n + 0] = rx;
            out[OFF_REACT + 3 * n + 1] = ry;
            out[OFF_REACT + 3 * n + 2] = rz;
        }

        // xyz_next = xyz + L * safe_normalize(residuals)
        float invr = (sr == 0.f) ? 1.f : (1.f / sqrtf(sr));
        px = px + L * (rx * invr);
        py = py + L * (ry * invr);
        pz = pz + L * (rz * invr);
    }
}

extern "C" void kernel_launch(void* const* d_in, const int* in_sizes, int n_in,
                              void* d_out, int out_size, void* d_ws, size_t ws_size,
                              hipStream_t stream) {
    const float* xyz0     = (const float*)d_in[0];
    const float* loads    = (const float*)d_in[1];
    const float* lengths0 = (const float*)d_in[2];
    const float* planes   = (const float*)d_in[3];
    const float* forces0  = (const float*)d_in[4];
    float* out = (float*)d_out;

    // block 0 = 16-step scan; blocks 1..48 cover the copy/zero segments
    // (max idx = 11520 < 48*256)
    cem_fused<<<49, 256, 0, stream>>>(xyz0, loads, lengths0, planes, forces0, out);
}

// Round 3
// 17.662 us; speedup vs baseline: 1.7190x; 1.1124x over previous
//
#include <hip/hip_runtime.h>

// Problem constants (fixed by setup_inputs):
//   N_TRAILS=256, N_STEPS=16, N_NODES=4096
//   trail edges: e = i*256+t (i<15), u=e, v=e+256
//   dev edges:   e = 3840 + i*255 + t (t<255), u=i*256+t, v=u+1
#define N_TRAILS 256
#define N_STEPS 16
#define N_NODES 4096
#define N_TRAIL_E 3840
#define N_DEV_E 4080
#define N_EDGES 7920

// d_out layout (f32, concatenated return order):
//   xyz (4096,3) | reactions (4096,3) | lengths (7920,1) | loads (4096,3) | forces (7920,1)
#define OFF_XYZ 0
#define OFF_REACT 12288
#define OFF_LEN 24576
#define OFF_LOADS 32496
#define OFF_FORCES 44784

// 8 scan waves (blocks 0..7): wave w owns core trails [32w, 32w+32) in lanes
// 16..47, plus a 16-trail halo on each side (lanes 0..15 / 48..63). The
// trail-coupling is a +-1 stencil per step, so after 16 steps the core lanes
// are exact while halo corruption (only at the block-0/7 array edges, or from
// the shfl wraparound) has advanced at most 15 lanes inward — never reaching
// the lanes the core reads. No LDS, no __syncthreads, neighbor access is pure
// in-wave shfl.
__global__ __launch_bounds__(64, 1) void cem_fused(
    const float* __restrict__ xyz0,
    const float* __restrict__ loads,
    const float* __restrict__ lengths0,
    const float* __restrict__ planes,
    const float* __restrict__ forces0,
    float* __restrict__ out) {
    const int lane = threadIdx.x;
    const int b = blockIdx.x;

    if (b >= 8) {
        // ---- copy/zero blocks (blocks 8..199), idx in [0, 12288) ----
        int idx = (b - 8) * 64 + lane;
        // zero reactions rows 0..14 (row 15 written by scan blocks)
        if (idx < (N_TRAIL_E * 3)) out[OFF_REACT + idx] = 0.0f;
        // loads passthrough
        if (idx < (N_NODES * 3)) out[OFF_LOADS + idx] = loads[idx];
        // deviation-edge forces passthrough
        if (idx < N_DEV_E) out[OFF_FORCES + N_TRAIL_E + idx] = forces0[N_TRAIL_E + idx];
        return;
    }

    // ---- scan blocks ----
    const int tr_raw = 32 * b - 16 + lane;                       // may be out of [0,256)
    const int tr = min(max(tr_raw, 0), N_TRAILS - 1);            // clamped load index
    const bool core = (lane >= 16) && (lane < 48);
    const bool has_left = (tr_raw > 0);                          // left dev edge exists
    const bool has_right = (tr_raw < N_TRAILS - 1);              // right dev edge exists

    // Preload all 16 steps' per-trail data into registers (latency paid once,
    // overlapped). ~192 floats/lane; __launch_bounds__(64,1) permits 512 VGPR.
    float pl[N_STEPS][3];   // loads[n]
    float pp[N_STEPS][6];   // planes[n]
    float l0[N_STEPS];      // lengths0[n]
    float fL[N_STEPS];      // forces0[left dev edge]
    float fR[N_STEPS];      // forces0[right dev edge]
#pragma unroll
    for (int i = 0; i < N_STEPS; ++i) {
        const int n = i * N_TRAILS + tr;
        pl[i][0] = loads[3 * n + 0];
        pl[i][1] = loads[3 * n + 1];
        pl[i][2] = loads[3 * n + 2];
        const float2* p2 = (const float2*)(planes + 6 * n);  // 8B-aligned
        float2 a = p2[0], bb = p2[1], c = p2[2];
        pp[i][0] = a.x;  pp[i][1] = a.y;  pp[i][2] = bb.x;
        pp[i][3] = bb.y; pp[i][4] = c.x;  pp[i][5] = c.y;
        l0[i] = lengths0[n];
        const int ebase = N_TRAIL_E + i * (N_TRAILS - 1);
        fL[i] = forces0[ebase + max(tr - 1, 0)];   // unused unless has_left
        fR[i] = forces0[ebase + min(tr, N_TRAILS - 2)];  // unused unless has_right
    }

    // row 0 positions = xyz0[trail]
    float px = xyz0[3 * tr + 0];
    float py = xyz0[3 * tr + 1];
    float pz = xyz0[3 * tr + 2];
    float rx = 0.f, ry = 0.f, rz = 0.f;  // residuals carry

#pragma unroll
    for (int i = 0; i < N_STEPS; ++i) {
        const int n = i * N_TRAILS + tr_raw;

        // xyz[row i] = position carried into this step (pre-update)
        if (core) {
            out[OFF_XYZ + 3 * n + 0] = px;
            out[OFF_XYZ + 3 * n + 1] = py;
            out[OFF_XYZ + 3 * n + 2] = pz;
        }

        // neighbor positions via in-wave shuffle (wraps at lane 0/63: halo-only)
        float lx = __shfl(px, lane - 1), ly = __shfl(py, lane - 1), lz = __shfl(pz, lane - 1);
        float qx = __shfl(px, lane + 1), qy = __shfl(py, lane + 1), qz = __shfl(pz, lane + 1);

        // deviation from the (at most 2) incident deviation edges of row i
        float dx = 0.f, dy = 0.f, dz = 0.f;
        if (has_left) {
            // edge eL: (i,t-1)->(i,t); incidence[eL,n] = -1; vec = x[t]-x[t-1]
            float vx = px - lx, vy = py - ly, vz = pz - lz;
            float s = vx * vx + vy * vy + vz * vz;
            float inv = (s == 0.f) ? 1.f : (1.f / sqrtf(s));
            float f = fL[i];
            dx -= f * (vx * inv);
            dy -= f * (vy * inv);
            dz -= f * (vz * inv);
        }
        if (has_right) {
            // edge eR: (i,t)->(i,t+1); incidence[eR,n] = +1; vec = x[t+1]-x[t]
            float vx = qx - px, vy = qy - py, vz = qz - pz;
            float s = vx * vx + vy * vy + vz * vz;
            float inv = (s == 0.f) ? 1.f : (1.f / sqrtf(s));
            float f = fR[i];
            dx += f * (vx * inv);
            dy += f * (vy * inv);
            dz += f * (vz * inv);
            // dev-edge length: row-i positions ARE final xyz for row i
            if (core) out[OFF_LEN + N_TRAIL_E + i * (N_TRAILS - 1) + tr_raw] = sqrtf(s);
        }

        // residuals = residuals - deviation - loads[n]
        rx = rx - dx - pl[i][0];
        ry = ry - dy - pl[i][1];
        rz = rz - dz - pl[i][2];

        // plane logic
        float ox = pp[i][0], oy = pp[i][1], oz = pp[i][2];
        float nx = pp[i][3], ny = pp[i][4], nz = pp[i][5];
        bool zero_n = (fabsf(nx) <= 1e-8f) && (fabsf(ny) <= 1e-8f) && (fabsf(nz) <= 1e-8f);
        if (zero_n) { nx = 1.f; ny = 1.f; nz = 1.f; }
        float cos_nop = zero_n ? 0.f
                               : (nx * (ox - px) + ny * (oy - py) + nz * (oz - pz));
        bool zero_r = (fabsf(rx) <= 1e-8f) && (fabsf(ry) <= 1e-8f) && (fabsf(rz) <= 1e-8f);
        float rsx = zero_r ? 1.f : rx;
        float rsy = zero_r ? 1.f : ry;
        float rsz = zero_r ? 1.f : rz;
        float s2 = rsx * rsx + rsy * rsy + rsz * rsz;
        float inv2 = (s2 == 0.f) ? 1.f : (1.f / sqrtf(s2));
        float denom = nx * (rsx * inv2) + ny * (rsy * inv2) + nz * (rsz * inv2);
        float len_plane = zero_r ? 0.f : (cos_nop / denom);
        float l0v = l0[i];
        float L = (l0v != 0.f) ? l0v : len_plane;

        float sr = rx * rx + ry * ry + rz * rz;
        float rn = sqrtf(sr);
        if (i < N_STEPS - 1) {
            if (core) {
                // trail edge e = i*256+t: force = |res| * sign(L>=0)
                out[OFF_FORCES + i * N_TRAILS + tr_raw] = rn * ((L < 0.f) ? -1.f : 1.f);
                // trail edge length = |xyz_next - xyz| = |L| (0 if res == 0)
                out[OFF_LEN + i * N_TRAILS + tr_raw] = (sr == 0.f) ? 0.f : fabsf(L);
            }
        } else if (core) {
            // reactions[row 15] = final residuals
            out[OFF_REACT + 3 * n + 0] = rx;
            out[OFF_REACT + 3 * n + 1] = ry;
            out[OFF_REACT + 3 * n + 2] = rz;
        }

        // xyz_next = xyz + L * safe_normalize(residuals)
        float invr = (sr == 0.f) ? 1.f : (1.f / sqrtf(sr));
        px = px + L * (rx * invr);
        py = py + L * (ry * invr);
        pz = pz + L * (rz * invr);
    }
}

extern "C" void kernel_launch(void* const* d_in, const int* in_sizes, int n_in,
                              void* d_out, int out_size, void* d_ws, size_t ws_size,
                              hipStream_t stream) {
    const float* xyz0     = (const float*)d_in[0];
    const float* loads    = (const float*)d_in[1];
    const float* lengths0 = (const float*)d_in[2];
    const float* planes   = (const float*)d_in[3];
    const float* forces0  = (const float*)d_in[4];
    float* out = (float*)d_out;

    // blocks 0..7: independent 64-lane scan waves (32 core trails each)
    // blocks 8..199: copy/zero segments (192*64 = 12288 covers the largest)
    cem_fused<<<200, 64, 0, stream>>>(xyz0, loads, lengths0, planes, forces0, out);
}